// Round 4
// baseline (936.261 us; speedup 1.0000x reference)
//
#include <hip/hip_runtime.h>
#include <hip/hip_bf16.h>

// Problem constants (fixed by reference setup_inputs)
#define NBATCH 128
#define TLEN   2048
#define FDIM   88
#define WIN    64
#define TT     256           // time-tile per block
#define FRAMES (TT + WIN)    // 320 staged frames
#define LSTR   100           // frame stride in bf16; 200B -> verified conflict-free (R2: BANK_CONFLICT=0)
#define BSLICE (18 * 512)    // 9216 elems per tau slice of fragment-packed Wt

typedef __attribute__((ext_vector_type(8))) short short8;   // 8 x bf16 (4 VGPR) MFMA A/B frag
typedef __attribute__((ext_vector_type(4))) short short4v;  // 8B LDS store
typedef __attribute__((ext_vector_type(4))) float floatx4;  // MFMA C/D frag

static __device__ __forceinline__ unsigned short f2bf(float f) {
    union { float f; unsigned int u; } a; a.f = f;
    unsigned int u = a.u;
    u += 0x7fffu + ((u >> 16) & 1u);   // round-to-nearest-even
    return (unsigned short)(u >> 16);
}

// Repack W (FDIM x WIN*FDIM, fp32) -> fragment-packed bf16:
//   Wt[tau][kk(0..2)][n_t(0..5)][lane(0..63)][j(0..7)]
// B-fragment for (tau,kk,n_t) is a contiguous 1KB block;
//   value = W[n][tau*88 + k], n = n_t*16 + (lane&15), k = kk*32 + (lane>>4)*8 + j
// (zero-padded where n>=88 or k>=88).
__global__ void prep_w(const float* __restrict__ W, unsigned short* __restrict__ Wt) {
    int idx = blockIdx.x * blockDim.x + threadIdx.x;
    if (idx >= WIN * BSLICE) return;
    int j    = idx & 7;
    int lane = (idx >> 3) & 63;
    int rest = idx >> 9;                             // (tau*3 + kk)*6 + n_t
    int nt   = rest % 6;
    int kkt  = rest / 6;
    int kk   = kkt % 3;
    int tau  = kkt / 3;
    int n = nt * 16 + (lane & 15);
    int k = kk * 32 + (lane >> 4) * 8 + j;
    float v = 0.f;
    if (n < FDIM && k < FDIM) v = W[n * (WIN * FDIM) + tau * FDIM + k];
    Wt[idx] = f2bf(v);
}

static __device__ __forceinline__ void load_bfrags(short8* dst, const unsigned short* __restrict__ Wt,
                                                   int tau, int kk, int nt0, int lane) {
    const unsigned short* p = Wt + (size_t)tau * BSLICE + (size_t)((kk * 6 + nt0) * 512) + lane * 8;
    #pragma unroll
    for (int n_t = 0; n_t < 3; ++n_t)
        dst[n_t] = *(const short8*)(p + n_t * 512);
}

static __device__ __forceinline__ void mfma_step(floatx4 acc[8][3], const short8* bf,
                                                 const unsigned short* xs, int a_tau, int kk) {
    short8 af[8];
    #pragma unroll
    for (int m_t = 0; m_t < 8; ++m_t)
        af[m_t] = *(const short8*)&xs[a_tau + m_t * 16 * LSTR + kk * 32];
    __builtin_amdgcn_s_setprio(1);
    #pragma unroll
    for (int m_t = 0; m_t < 8; ++m_t)
        #pragma unroll
        for (int n_t = 0; n_t < 3; ++n_t)
            acc[m_t][n_t] = __builtin_amdgcn_mfma_f32_16x16x32_bf16(
                af[m_t], bf[n_t], acc[m_t][n_t], 0, 0, 0);
    __builtin_amdgcn_s_setprio(0);
}

// out[nb, t0+tr, fo] = b[fo] + sum_{tau,fi} x[nb, t0+tr-64+tau, fi] * W[fo, tau*88+fi]
// 4 waves (2 row x 2 col), each wave owns 128 rows (time) x 48 cols (f_out).
// 128-row waves halve B bytes per FLOP (the R1/R2 bottleneck); B stays in the
// global->L1 path (LDS-B was the R2 regression); raw per-tau s_barrier keeps
// waves on the same Wt slice for L1 hits; B is reg-double-buffered 1 kk ahead.
__global__ __launch_bounds__(256, 2) void conv_mfma(
    const float* __restrict__ x, const unsigned short* __restrict__ Wt,
    const float* __restrict__ bias, float* __restrict__ out)
{
    __shared__ unsigned short xs[FRAMES * LSTR];    // 64,000 B -> 2 blocks/CU

    const int tb  = blockIdx.x;
    const int nb  = blockIdx.y;
    const int t0  = tb * TT;
    const int tid = threadIdx.x;

    const int wave = tid >> 6;
    const int lane = tid & 63;
    const int m    = lane & 15;        // MFMA row/col-in-frag index
    const int quad = lane >> 4;        // k-subgroup
    const int wrow = (wave >> 1) * 128;// wave row offset (time)
    const int wcol = (wave & 1) * 48;  // wave col offset (f_out)
    const int nt0  = (wave & 1) * 3;   // first n_t slot in the tau slice

    // issue first B fragment loads early; L2 latency hides under xs staging
    short8 bA[3], bB[3];
    load_bfrags(bA, Wt, 0, 0, nt0, lane);

    // ---- stage x tile: frames [t0-64, t0+TT-1], bf16, zero-padded (time & feature) ----
    const float* xn = x + (size_t)nb * TLEN * FDIM;
    for (int idx = tid; idx < FRAMES * 25; idx += 256) {   // 25 float4-slots (22 real, 3 zero-pad)
        int i = idx / 25;
        int c = idx % 25;
        int g = t0 - WIN + i;
        short4v v = (short4v){0, 0, 0, 0};
        if (c < 22 && g >= 0) {
            float4 f = *((const float4*)(xn + (size_t)g * FDIM) + c);
            v.x = (short)f2bf(f.x); v.y = (short)f2bf(f.y);
            v.z = (short)f2bf(f.z); v.w = (short)f2bf(f.w);
        }
        *(short4v*)&xs[i * LSTR + c * 4] = v;
    }
    __syncthreads();

    floatx4 acc[8][3] = {};            // [m_t 16-row tiles][n_t 16-col tiles]
    const int a_base = (wrow + m) * LSTR + quad * 8;

    // tau unrolled x2 so B double-buffer indices are static (no scratch spill)
    for (int tau = 0; tau < WIN; tau += 2) {
        const int at0 = a_base + tau * LSTR;
        const int at1 = at0 + LSTR;
        __builtin_amdgcn_s_barrier();          // raw barrier: L1 alignment, no vmcnt drain
        load_bfrags(bB, Wt, tau, 1, nt0, lane);
        mfma_step(acc, bA, xs, at0, 0);
        load_bfrags(bA, Wt, tau, 2, nt0, lane);
        mfma_step(acc, bB, xs, at0, 1);
        load_bfrags(bB, Wt, tau + 1, 0, nt0, lane);
        mfma_step(acc, bA, xs, at0, 2);
        __builtin_amdgcn_s_barrier();
        load_bfrags(bA, Wt, tau + 1, 1, nt0, lane);
        mfma_step(acc, bB, xs, at1, 0);
        load_bfrags(bB, Wt, tau + 1, 2, nt0, lane);
        mfma_step(acc, bA, xs, at1, 1);
        if (tau + 2 < WIN)
            load_bfrags(bA, Wt, tau + 2, 0, nt0, lane);
        mfma_step(acc, bB, xs, at1, 2);
    }

    // ---- epilogue: D layout col=lane&15, row=quad*4+reg; add bias; write both tuple halves ----
    float bv[3];
    #pragma unroll
    for (int n_t = 0; n_t < 3; ++n_t) {
        int c = wcol + n_t * 16 + m;
        bv[n_t] = (c < FDIM) ? bias[c] : 0.f;
    }
    const size_t half = (size_t)NBATCH * TLEN * FDIM;
    #pragma unroll
    for (int n_t = 0; n_t < 3; ++n_t) {
        int c = wcol + n_t * 16 + m;
        if (c >= FDIM) continue;
        #pragma unroll
        for (int m_t = 0; m_t < 8; ++m_t) {
            #pragma unroll
            for (int reg = 0; reg < 4; ++reg) {
                int tr = wrow + m_t * 16 + quad * 4 + reg;
                size_t off = ((size_t)nb * TLEN + (t0 + tr)) * FDIM + c;
                float v = acc[m_t][n_t][reg] + bv[n_t];
                out[off] = v;
                out[half + off] = v;
            }
        }
    }
}

extern "C" void kernel_launch(void* const* d_in, const int* in_sizes, int n_in,
                              void* d_out, int out_size, void* d_ws, size_t ws_size,
                              hipStream_t stream) {
    const float* x = (const float*)d_in[0];
    const float* W = (const float*)d_in[1];
    const float* b = (const float*)d_in[2];
    float* out = (float*)d_out;
    unsigned short* Wt = (unsigned short*)d_ws;   // 64*18*512*2 = 1,179,648 B

    prep_w<<<(WIN * BSLICE + 255) / 256, 256, 0, stream>>>(W, Wt);
    dim3 grid(TLEN / TT, NBATCH);
    conv_mfma<<<grid, 256, 0, stream>>>(x, Wt, b, out);
}

// Round 6
// 662.942 us; speedup vs baseline: 1.4123x; 1.4123x over previous
//
#include <hip/hip_runtime.h>
#include <hip/hip_bf16.h>

// Problem constants (fixed by reference setup_inputs)
#define NBATCH 128
#define TLEN   2048
#define FDIM   88
#define WIN    64
#define TT     256           // time-tile per block
#define FRAMES (TT + WIN)    // 320 staged frames
#define LSTR   100           // frame stride in bf16; 200B -> verified conflict-free (R2: BANK_CONFLICT=0)
#define BSLICE (18 * 512)    // 9216 elems per tau slice of fragment-packed Wt

typedef __attribute__((ext_vector_type(8))) short short8;   // 8 x bf16 (4 VGPR) MFMA A/B frag
typedef __attribute__((ext_vector_type(4))) short short4v;  // 8B LDS store
typedef __attribute__((ext_vector_type(4))) float floatx4;  // MFMA C/D frag

static __device__ __forceinline__ unsigned short f2bf(float f) {
    union { float f; unsigned int u; } a; a.f = f;
    unsigned int u = a.u;
    u += 0x7fffu + ((u >> 16) & 1u);   // round-to-nearest-even
    return (unsigned short)(u >> 16);
}

// Repack W (FDIM x WIN*FDIM, fp32) -> fragment-packed bf16:
//   Wt[tau][kk(0..2)][n_t(0..5)][lane(0..63)][j(0..7)]
// B-fragment for (tau,kk,n_t) is a contiguous 1KB block;
//   value = W[n][tau*88 + k], n = n_t*16 + (lane&15), k = kk*32 + (lane>>4)*8 + j
// (zero-padded where n>=88 or k>=88).
__global__ void prep_w(const float* __restrict__ W, unsigned short* __restrict__ Wt) {
    int idx = blockIdx.x * blockDim.x + threadIdx.x;
    if (idx >= WIN * BSLICE) return;
    int j    = idx & 7;
    int lane = (idx >> 3) & 63;
    int rest = idx >> 9;                             // (tau*3 + kk)*6 + n_t
    int nt   = rest % 6;
    int kkt  = rest / 6;
    int kk   = kkt % 3;
    int tau  = kkt / 3;
    int n = nt * 16 + (lane & 15);
    int k = kk * 32 + (lane >> 4) * 8 + j;
    float v = 0.f;
    if (n < FDIM && k < FDIM) v = W[n * (WIN * FDIM) + tau * FDIM + k];
    Wt[idx] = f2bf(v);
}

// load the 6 B-fragments (96 output cols) for one (tau, kk) step
static __device__ __forceinline__ void load6(short8* dst, const unsigned short* __restrict__ Wt,
                                             int tau, int kk, int lane) {
    const unsigned short* p = Wt + (size_t)tau * BSLICE + (size_t)(kk * 6 * 512) + lane * 8;
    #pragma unroll
    for (int n_t = 0; n_t < 6; ++n_t)
        dst[n_t] = *(const short8*)(p + n_t * 512);
}

// one kk-step: 4 A-frag LDS reads + 24 MFMAs (64 rows x 96 cols, K=32)
static __device__ __forceinline__ void mfma_step(floatx4 acc[4][6], const short8* bf,
                                                 const unsigned short* xs, int a_off) {
    short8 af[4];
    #pragma unroll
    for (int m_t = 0; m_t < 4; ++m_t)
        af[m_t] = *(const short8*)&xs[a_off + m_t * 16 * LSTR];
    __builtin_amdgcn_s_setprio(1);
    #pragma unroll
    for (int m_t = 0; m_t < 4; ++m_t)
        #pragma unroll
        for (int n_t = 0; n_t < 6; ++n_t)
            acc[m_t][n_t] = __builtin_amdgcn_mfma_f32_16x16x32_bf16(
                af[m_t], bf[n_t], acc[m_t][n_t], 0, 0, 0);
    __builtin_amdgcn_s_setprio(0);
}

// out[nb, t0+tr, fo] = b[fo] + sum_{tau,fi} x[nb, t0+tr-64+tau, fi] * W[fo, tau*88+fi]
// 4 waves, each owns 64 rows (time) x 96 cols (f_out) -- the R1 config (best
// measured: 321us, MfmaUtil 42%). Change vs R1: B fragments in an explicit
// 3-buffer register rotation (reload right after use, next use 3 kk-steps
// later -> ~500-700 cyc of guaranteed L2-latency cover). No barriers.
__global__ __launch_bounds__(256, 2) void conv_mfma(
    const float* __restrict__ x, const unsigned short* __restrict__ Wt,
    const float* __restrict__ bias, float* __restrict__ out)
{
    __shared__ unsigned short xs[FRAMES * LSTR];    // 64,000 B -> 2 blocks/CU

    const int tb  = blockIdx.x;
    const int nb  = blockIdx.y;
    const int t0  = tb * TT;
    const int tid = threadIdx.x;

    const int wave = tid >> 6;
    const int lane = tid & 63;
    const int m    = lane & 15;        // MFMA row/col-in-frag index
    const int quad = lane >> 4;        // k-subgroup
    const int wrow = wave * 64;        // wave row offset (time)

    // issue tau=0's three B-step loads NOW; the staging __syncthreads drains them
    short8 b0[6], b1[6], b2[6];
    load6(b0, Wt, 0, 0, lane);
    load6(b1, Wt, 0, 1, lane);
    load6(b2, Wt, 0, 2, lane);

    // ---- stage x tile: frames [t0-64, t0+TT-1], bf16, zero-padded (time & feature) ----
    const float* xn = x + (size_t)nb * TLEN * FDIM;
    for (int idx = tid; idx < FRAMES * 25; idx += 256) {   // 25 float4-slots (22 real, 3 zero-pad)
        int i = idx / 25;
        int c = idx % 25;
        int g = t0 - WIN + i;
        short4v v = (short4v){0, 0, 0, 0};
        if (c < 22 && g >= 0) {
            float4 f = *((const float4*)(xn + (size_t)g * FDIM) + c);
            v.x = (short)f2bf(f.x); v.y = (short)f2bf(f.y);
            v.z = (short)f2bf(f.z); v.w = (short)f2bf(f.w);
        }
        *(short4v*)&xs[i * LSTR + c * 4] = v;
    }
    __syncthreads();

    floatx4 acc[4][6] = {};            // [m_t 16-row tiles][n_t 16-col tiles]
    const int a_base = (wrow + m) * LSTR + quad * 8;

    for (int tau = 0; tau < WIN - 1; ++tau) {
        const int at = a_base + tau * LSTR;
        mfma_step(acc, b0, xs, at);          load6(b0, Wt, tau + 1, 0, lane);
        mfma_step(acc, b1, xs, at + 32);     load6(b1, Wt, tau + 1, 1, lane);
        mfma_step(acc, b2, xs, at + 64);     load6(b2, Wt, tau + 1, 2, lane);
    }
    {   // peeled last tau (no prefetch)
        const int at = a_base + (WIN - 1) * LSTR;
        mfma_step(acc, b0, xs, at);
        mfma_step(acc, b1, xs, at + 32);
        mfma_step(acc, b2, xs, at + 64);
    }

    // ---- epilogue: D layout col=lane&15, row=quad*4+reg; add bias; write both tuple halves ----
    float bv[6];
    #pragma unroll
    for (int n_t = 0; n_t < 6; ++n_t) {
        int c = n_t * 16 + m;
        bv[n_t] = (c < FDIM) ? bias[c] : 0.f;
    }
    const size_t half = (size_t)NBATCH * TLEN * FDIM;
    #pragma unroll
    for (int n_t = 0; n_t < 6; ++n_t) {
        int c = n_t * 16 + m;
        if (c >= FDIM) continue;
        #pragma unroll
        for (int m_t = 0; m_t < 4; ++m_t) {
            #pragma unroll
            for (int reg = 0; reg < 4; ++reg) {
                int tr = wrow + m_t * 16 + quad * 4 + reg;
                size_t off = ((size_t)nb * TLEN + (t0 + tr)) * FDIM + c;
                float v = acc[m_t][n_t][reg] + bv[n_t];
                out[off] = v;
                out[half + off] = v;
            }
        }
    }
}

extern "C" void kernel_launch(void* const* d_in, const int* in_sizes, int n_in,
                              void* d_out, int out_size, void* d_ws, size_t ws_size,
                              hipStream_t stream) {
    const float* x = (const float*)d_in[0];
    const float* W = (const float*)d_in[1];
    const float* b = (const float*)d_in[2];
    float* out = (float*)d_out;
    unsigned short* Wt = (unsigned short*)d_ws;   // 64*18*512*2 = 1,179,648 B

    prep_w<<<(WIN * BSLICE + 255) / 256, 256, 0, stream>>>(W, Wt);
    dim3 grid(TLEN / TT, NBATCH);
    conv_mfma<<<grid, 256, 0, stream>>>(x, Wt, b, out);
}